// Round 1
// baseline (165.773 us; speedup 1.0000x reference)
//
#include <hip/hip_runtime.h>

// Problem constants
constexpr int B_TOT = 8192;      // batch
constexpr int NM    = 64;        // n_models
constexpr int TT    = 16;        // trees per split
constexpr int LF    = 64;        // maxleaf
constexpr int EM    = 32;        // emb dim
constexpr int XROW  = NM * TT;   // 1024 ints per x row
constexpr int TROWS = TT * LF;   // 1024 rows per model table

// ---------------------------------------------------------------------------
// K1: per-channel batch statistics.
// h[b,m,e] = sum_t tbl[m][x[b,m*16+t] + 64*t][e]; accumulate sum and sum^2
// over b for each channel (m,e).
// Grid: 4096 blocks = 64 models x 64 chunks (128 b's each).
// Block: 256 = 32 e-lanes x 8 groups (16 b's per group-thread).
// tq-outer loop keeps the per-phase table hot set at 32KB (L1-sized).
// m = blockIdx & 63 -> same-m blocks round-robin onto the same XCD (L2 local).
// ---------------------------------------------------------------------------
__global__ __launch_bounds__(256) void k_stats(
    const int* __restrict__ x, const float* __restrict__ tbl,
    float* __restrict__ wsum, float* __restrict__ wsumsq)
{
    const int m     = blockIdx.x & 63;
    const int chunk = blockIdx.x >> 6;      // 0..63
    const int e     = threadIdx.x & 31;
    const int grp   = threadIdx.x >> 5;     // 0..7
    const float* __restrict__ tblm = tbl + m * (TROWS * EM);
    const int*   __restrict__ xm   = x + m * TT;
    const int b0 = chunk * 128 + grp * 16;

    float h[16];
#pragma unroll
    for (int i = 0; i < 16; ++i) h[i] = 0.f;

#pragma unroll
    for (int tq = 0; tq < 4; ++tq) {
        const int rbase = tq * 256;          // (tq*4)*64
#pragma unroll
        for (int bb = 0; bb < 16; ++bb) {
            const int b = b0 + bb;
            const int4 q = *(const int4*)(xm + (size_t)b * XROW + tq * 4);
            h[bb] += tblm[(q.x + rbase      ) * EM + e]
                   + tblm[(q.y + rbase +  64) * EM + e]
                   + tblm[(q.z + rbase + 128) * EM + e]
                   + tblm[(q.w + rbase + 192) * EM + e];
        }
    }

    float s = 0.f, s2 = 0.f;
#pragma unroll
    for (int i = 0; i < 16; ++i) { s += h[i]; s2 += h[i] * h[i]; }

    __shared__ float ls[256];
    __shared__ float ls2[256];
    ls[threadIdx.x] = s; ls2[threadIdx.x] = s2;
    __syncthreads();
    if (grp == 0) {
#pragma unroll
        for (int g = 1; g < 8; ++g) { s += ls[g * 32 + e]; s2 += ls2[g * 32 + e]; }
        atomicAdd(&wsum[m * EM + e], s);
        atomicAdd(&wsumsq[m * EM + e], s2);
    }
}

// ---------------------------------------------------------------------------
// K2: fold BN + output projection into per-leaf dot table.
//   a[m,e] = invstd*gamma*w ; C[m] = bout_b[m] + sum_e (beta - mean*invstd*gamma)*w
//   g2[row*64 + m] = sum_e tbl[m][row][e] * a[m,e]      (row = t*64 + r)
// Grid: 64 blocks (one per model), 256 threads.
// ---------------------------------------------------------------------------
__global__ __launch_bounds__(256) void k_prep(
    const float* __restrict__ tbl,
    const float* __restrict__ gamma, const float* __restrict__ beta,
    const float* __restrict__ bw, const float* __restrict__ bb,
    const float* __restrict__ wsum, const float* __restrict__ wsumsq,
    float* __restrict__ Cm, float* __restrict__ g2)
{
    const int m = blockIdx.x;
    __shared__ float a_s[EM];
    if (threadIdx.x < EM) {
        const int e  = threadIdx.x;
        const int ch = m * EM + e;
        const float inv_n = 1.f / (float)B_TOT;
        const float mean = wsum[ch] * inv_n;
        const float var  = wsumsq[ch] * inv_n - mean * mean;
        const float istd = rsqrtf(var + 1e-5f);
        const float g = gamma[ch];
        const float w = bw[ch];              // bout_w flat (m,e)
        a_s[e] = istd * g * w;
        float ct = (beta[ch] - mean * istd * g) * w;
#pragma unroll
        for (int off = 16; off > 0; off >>= 1) ct += __shfl_down(ct, off, 32);
        if (e == 0) Cm[m] = bb[m] + ct;
    }
    __syncthreads();

    const float* __restrict__ tblm = tbl + m * (TROWS * EM);
    for (int row = threadIdx.x; row < TROWS; row += 256) {
        const float4* rp = (const float4*)(tblm + row * EM);
        float acc = 0.f;
#pragma unroll
        for (int i = 0; i < 8; ++i) {
            const float4 v = rp[i];
            acc += v.x * a_s[i*4+0] + v.y * a_s[i*4+1]
                 + v.z * a_s[i*4+2] + v.w * a_s[i*4+3];
        }
        g2[row * NM + m] = acc;
    }
}

// ---------------------------------------------------------------------------
// K3: out[b,m] = C[m] + sum_t g2[(t*64 + x[b,m*16+t])*64 + m]; sum over m.
// Wave per b, lane = m (x row read fully coalesced: 4KB/wave).
// Per-t 16KB slab of g2 double-buffered through LDS; slab layout [r][m]
// -> gather bank = m & 31 : 2 lanes/bank (free).
// Grid: 1024 blocks x 512 threads (8 waves = 8 b's per block).
// ---------------------------------------------------------------------------
__global__ __launch_bounds__(512) void k_out(
    const int* __restrict__ x, const float* __restrict__ g2,
    const float* __restrict__ Cm, float* __restrict__ out)
{
    __shared__ float slab[2][LF * NM];       // 2 x 16KB
    const int tid  = threadIdx.x;
    const int wid  = tid >> 6;
    const int lane = tid & 63;               // = m
    const int b    = blockIdx.x * 8 + wid;

    const int4* xp = (const int4*)(x + (size_t)b * XROW + lane * TT);
    const int4 q0 = xp[0], q1 = xp[1], q2 = xp[2], q3 = xp[3];
    const int idxs[16] = {q0.x,q0.y,q0.z,q0.w, q1.x,q1.y,q1.z,q1.w,
                          q2.x,q2.y,q2.z,q2.w, q3.x,q3.y,q3.z,q3.w};

    // stage slab for t=0
    {
        const float4* src = (const float4*)(g2);
        const float4 v0 = src[tid * 2], v1 = src[tid * 2 + 1];
        float4* dst = (float4*)slab[0];
        dst[tid * 2] = v0; dst[tid * 2 + 1] = v1;
    }

    float acc = 0.f;
#pragma unroll
    for (int t = 0; t < 16; ++t) {
        __syncthreads();                     // slab[t&1] ready
        const float v = slab[t & 1][idxs[t] * NM + lane];
        if (t < 15) {                        // prefetch next slab into other buffer
            const float4* src = (const float4*)(g2 + (size_t)(t + 1) * (LF * NM));
            const float4 v0 = src[tid * 2], v1 = src[tid * 2 + 1];
            float4* dst = (float4*)slab[(t + 1) & 1];
            dst[tid * 2] = v0; dst[tid * 2 + 1] = v1;
        }
        acc += v;
    }

    const float o = acc + Cm[lane];
    float s = o;
#pragma unroll
    for (int off = 32; off > 0; off >>= 1) s += __shfl_down(s, off);
    out[B_TOT + (size_t)b * NM + lane] = o;  // out tensor (B, M)
    if (lane == 0) out[b] = s;               // sum_out (B, 1)
}

// ---------------------------------------------------------------------------
extern "C" void kernel_launch(void* const* d_in, const int* in_sizes, int n_in,
                              void* d_out, int out_size, void* d_ws, size_t ws_size,
                              hipStream_t stream) {
    const int*   x       = (const int*)d_in[0];
    const float* embed_w = (const float*)d_in[1];
    const float* gamma   = (const float*)d_in[2];
    const float* beta    = (const float*)d_in[3];
    const float* bout_w  = (const float*)d_in[4];
    const float* bout_b  = (const float*)d_in[5];
    float* out = (float*)d_out;

    float* ws     = (float*)d_ws;
    float* wsum   = ws;           // 2048
    float* wsumsq = ws + 2048;    // 2048
    float* Cm     = ws + 4096;    // 64
    float* g2     = ws + 4160;    // 64*1024 = 65536  (total ~273KB)

    // stats accumulators must start at zero (ws is poisoned each launch)
    hipMemsetAsync(wsum, 0, 4096 * sizeof(float), stream);

    k_stats<<<dim3(4096), dim3(256), 0, stream>>>(x, embed_w, wsum, wsumsq);
    k_prep <<<dim3(64),   dim3(256), 0, stream>>>(embed_w, gamma, beta, bout_w,
                                                  bout_b, wsum, wsumsq, Cm, g2);
    k_out  <<<dim3(1024), dim3(512), 0, stream>>>(x, g2, Cm, out);
}

// Round 3
// 141.793 us; speedup vs baseline: 1.1691x; 1.1691x over previous
//
#include <hip/hip_runtime.h>

// Problem constants
constexpr int B_TOT = 8192;      // batch
constexpr int NM    = 64;        // n_models
constexpr int TT    = 16;        // trees per split
constexpr int LF    = 64;        // maxleaf
constexpr int EM    = 32;        // emb dim
constexpr int XROW  = NM * TT;   // 1024 ints per x row
constexpr int TROWS = TT * LF;   // 1024 rows per model table

// ---------------------------------------------------------------------------
// K1: per-channel batch statistics.
// h[b,m,e] = sum_t tbl[m][x[b,m*16+t] + 64*t][e]; accumulate sum and sum^2
// over b per channel (m,e).
// Lane layout: f = tid&7 (float4 column of the 128B row), grp = tid>>3.
// One wave gather instr = global_load_dwordx4 covering 8 rows x 16B (vs a
// dword covering 2 rows) -> 4x fewer wave mem instrs + 4x less addr VALU.
// Grid: 4096 blocks = 64 models x 64 chunks (128 b's each); 4 b's per thread.
// tq-outer blocking keeps the hot table slice at 32KB (L1-sized).
// ---------------------------------------------------------------------------
__global__ __launch_bounds__(256) void k_stats(
    const int* __restrict__ x, const float* __restrict__ tbl,
    float* __restrict__ wsum, float* __restrict__ wsumsq)
{
    const int m     = blockIdx.x & 63;
    const int chunk = blockIdx.x >> 6;      // 0..63
    const int f     = threadIdx.x & 7;      // float4 within row
    const int grp   = threadIdx.x >> 3;     // 0..31
    const float4* __restrict__ tbl4 = (const float4*)(tbl + (size_t)m * (TROWS * EM));
    const int b0 = chunk * 128 + grp * 4;
    const int* __restrict__ xb = x + (size_t)b0 * XROW + m * TT;

    float4 h[4];
#pragma unroll
    for (int i = 0; i < 4; ++i) h[i] = make_float4(0.f, 0.f, 0.f, 0.f);

#pragma unroll
    for (int tq = 0; tq < 4; ++tq) {
        const int rbase = tq * 256;          // 64 * (tq*4)
#pragma unroll
        for (int bb = 0; bb < 4; ++bb) {
            const int4 q = *(const int4*)(xb + (size_t)bb * XROW + tq * 4);
            const float4 v0 = tbl4[(q.x + rbase      ) * 8 + f];
            const float4 v1 = tbl4[(q.y + rbase +  64) * 8 + f];
            const float4 v2 = tbl4[(q.z + rbase + 128) * 8 + f];
            const float4 v3 = tbl4[(q.w + rbase + 192) * 8 + f];
            h[bb].x += v0.x + v1.x + v2.x + v3.x;
            h[bb].y += v0.y + v1.y + v2.y + v3.y;
            h[bb].z += v0.z + v1.z + v2.z + v3.z;
            h[bb].w += v0.w + v1.w + v2.w + v3.w;
        }
    }

    float4 s  = make_float4(0.f, 0.f, 0.f, 0.f);
    float4 s2 = make_float4(0.f, 0.f, 0.f, 0.f);
#pragma unroll
    for (int i = 0; i < 4; ++i) {
        s.x += h[i].x;  s.y += h[i].y;  s.z += h[i].z;  s.w += h[i].w;
        s2.x += h[i].x * h[i].x;  s2.y += h[i].y * h[i].y;
        s2.z += h[i].z * h[i].z;  s2.w += h[i].w * h[i].w;
    }

    __shared__ float4 ls[32][8];
    __shared__ float4 ls2[32][8];
    ls[grp][f] = s; ls2[grp][f] = s2;
    __syncthreads();
    if (threadIdx.x < 32) {
        const int e  = threadIdx.x;          // channel 0..31
        const int fr = e >> 2, j = e & 3;
        float a = 0.f, a2 = 0.f;
#pragma unroll
        for (int g = 0; g < 32; ++g) {
            a  += ((const float*)&ls[g][fr])[j];
            a2 += ((const float*)&ls2[g][fr])[j];
        }
        atomicAdd(&wsum[m * EM + e], a);
        atomicAdd(&wsumsq[m * EM + e], a2);
    }
}

// ---------------------------------------------------------------------------
// K2: fold BN + output projection into a per-leaf dot table.
//   a[m,e] = invstd*gamma*w ; C[m] = bout_b[m] + sum_e (beta - mean*invstd*gamma)*w
//   g2[row*64 + m] = sum_e tbl[m][row][e] * a[m,e]      (row = t*64 + r)
// Grid: 256 blocks = 64 models x 4 row-quarters (256 rows each), 256 threads.
// ---------------------------------------------------------------------------
__global__ __launch_bounds__(256) void k_prep(
    const float* __restrict__ tbl,
    const float* __restrict__ gamma, const float* __restrict__ beta,
    const float* __restrict__ bw, const float* __restrict__ bb,
    const float* __restrict__ wsum, const float* __restrict__ wsumsq,
    float* __restrict__ Cm, float* __restrict__ g2)
{
    const int m    = blockIdx.x >> 2;
    const int part = blockIdx.x & 3;
    __shared__ float a_s[EM];
    if (threadIdx.x < EM) {
        const int e  = threadIdx.x;
        const int ch = m * EM + e;
        const float inv_n = 1.f / (float)B_TOT;
        const float mean = wsum[ch] * inv_n;
        const float var  = wsumsq[ch] * inv_n - mean * mean;
        const float istd = rsqrtf(var + 1e-5f);
        const float g = gamma[ch];
        const float w = bw[ch];              // bout_w flat (m,e)
        a_s[e] = istd * g * w;
        float ct = (beta[ch] - mean * istd * g) * w;
#pragma unroll
        for (int off = 16; off > 0; off >>= 1) ct += __shfl_down(ct, off, 32);
        if (e == 0 && part == 0) Cm[m] = bb[m] + ct;
    }
    __syncthreads();

    const float* __restrict__ tblm = tbl + (size_t)m * (TROWS * EM);
    const int row = part * 256 + threadIdx.x;
    const float4* rp = (const float4*)(tblm + row * EM);
    float acc = 0.f;
#pragma unroll
    for (int i = 0; i < 8; ++i) {
        const float4 v = rp[i];
        acc += v.x * a_s[i*4+0] + v.y * a_s[i*4+1]
             + v.z * a_s[i*4+2] + v.w * a_s[i*4+3];
    }
    g2[row * NM + m] = acc;
}

// ---------------------------------------------------------------------------
// K3: out[b,m] = C[m] + sum_t g2[(t*64 + x[b,m*16+t])*64 + m]; sum over m.
// Wave per b, lane = m (x row read fully coalesced: 4KB/wave).
// g2 = 256KB total > 160KB LDS cap -> stage in TWO 128KB phases (8 t-slabs
// each): 3 barriers per block instead of 16. Slab gather bank = m&31
// -> 2 lanes/bank = free.
// Grid: 512 blocks x 1024 threads (16 b's per block). 1 block/CU, 16 waves.
// ---------------------------------------------------------------------------
__global__ __launch_bounds__(1024) void k_out(
    const int* __restrict__ x, const float* __restrict__ g2,
    const float* __restrict__ Cm, float* __restrict__ out)
{
    __shared__ float slab[8 * LF * NM];      // 128KB = half of g2
    const int tid  = threadIdx.x;
    const int wid  = tid >> 6;               // 0..15
    const int lane = tid & 63;               // = m
    const int b    = blockIdx.x * 16 + wid;

    const int4* xp = (const int4*)(x + (size_t)b * XROW + lane * TT);
    const int4 q0 = xp[0], q1 = xp[1], q2 = xp[2], q3 = xp[3];
    const int idxs[16] = {q0.x,q0.y,q0.z,q0.w, q1.x,q1.y,q1.z,q1.w,
                          q2.x,q2.y,q2.z,q2.w, q3.x,q3.y,q3.z,q3.w};

    float acc = 0.f;
#pragma unroll
    for (int half = 0; half < 2; ++half) {
        if (half == 1) __syncthreads();      // done reading previous slab
        // stage 128KB: 1024 threads x 8 float4, coalesced
        const float4* src = (const float4*)(g2 + (size_t)half * (8 * LF * NM));
        float4* dst = (float4*)slab;
#pragma unroll
        for (int j = 0; j < 8; ++j) dst[tid + j * 1024] = src[tid + j * 1024];
        __syncthreads();
#pragma unroll
        for (int tt = 0; tt < 8; ++tt) {
            const int t = half * 8 + tt;
            acc += slab[tt * (LF * NM) + idxs[t] * NM + lane];
        }
    }

    const float o = acc + Cm[lane];
    float s = o;
#pragma unroll
    for (int off = 32; off > 0; off >>= 1) s += __shfl_down(s, off);
    out[B_TOT + (size_t)b * NM + lane] = o;  // out tensor (B, M)
    if (lane == 0) out[b] = s;               // sum_out (B, 1)
}

// ---------------------------------------------------------------------------
extern "C" void kernel_launch(void* const* d_in, const int* in_sizes, int n_in,
                              void* d_out, int out_size, void* d_ws, size_t ws_size,
                              hipStream_t stream) {
    const int*   x       = (const int*)d_in[0];
    const float* embed_w = (const float*)d_in[1];
    const float* gamma   = (const float*)d_in[2];
    const float* beta    = (const float*)d_in[3];
    const float* bout_w  = (const float*)d_in[4];
    const float* bout_b  = (const float*)d_in[5];
    float* out = (float*)d_out;

    float* ws     = (float*)d_ws;
    float* wsum   = ws;           // 2048
    float* wsumsq = ws + 2048;    // 2048
    float* Cm     = ws + 4096;    // 64
    float* g2     = ws + 4160;    // 65536

    // stats accumulators must start at zero (ws is poisoned each launch)
    (void)hipMemsetAsync(wsum, 0, 4096 * sizeof(float), stream);

    k_stats<<<dim3(4096), dim3(256), 0, stream>>>(x, embed_w, wsum, wsumsq);
    k_prep <<<dim3(256),  dim3(256), 0, stream>>>(embed_w, gamma, beta, bout_w,
                                                  bout_b, wsum, wsumsq, Cm, g2);
    k_out  <<<dim3(512),  dim3(1024), 0, stream>>>(x, g2, Cm, out);
}